// Round 9
// baseline (2356.603 us; speedup 1.0000x reference)
//
#include <hip/hip_runtime.h>
#include <hip/hip_bf16.h>
#include <math.h>

namespace {
constexpr int KNB  = 7;                  // neighbor volumes
constexpr int PS   = 7;                  // patch size
constexpr int CCH  = 3;                  // image channels
constexpr int IH   = 256;
constexpr int IW   = 256;
constexpr int PADR = 3;                  // PS/2
constexpr int QN   = IH * IW;            // 65536
constexpr int ON   = 32;                 // candidates per query
constexpr int EN   = 64;                 // embedding dim
constexpr int FN   = CCH * PS * PS;      // 147
constexpr int KC   = KNB * CCH;          // 21 output channels per map
constexpr int TQY  = 8;                  // tile rows
constexpr int TQX  = 4;                  // tile cols (= waves per block)
constexpr int CHY  = TQY + PS - 1;       // 14
constexpr int CHX  = TQX + PS - 1;       // 10
constexpr int CELEM = KC * CHY * CHX;    // 2940 canvas floats
constexpr int NW   = 4;                  // waves per block
constexpr int NBX  = IW / TQX;           // 64
constexpr int NBY  = IH / TQY;           // 32
}

__device__ __forceinline__ float bf16_to_f(unsigned short u) {
    union { unsigned int i; float f; } c;
    c.i = ((unsigned int)u) << 16;
    return c.f;
}

// x fp32 -> bf16 (RNE), vectorized 4-wide. Packed [N][147] rows.
__global__ __launch_bounds__(256) void conv_kernel(
    const float* __restrict__ x, unsigned short* __restrict__ xb, int n4)
{
    int i = blockIdx.x * blockDim.x + threadIdx.x;
    if (i >= n4) return;
    float4 v = ((const float4*)x)[i];
    ushort4 o;
    o.x = __hip_bfloat16_raw(__float2bfloat16(v.x)).x;
    o.y = __hip_bfloat16_raw(__float2bfloat16(v.y)).x;
    o.z = __hip_bfloat16_raw(__float2bfloat16(v.z)).x;
    o.w = __hip_bfloat16_raw(__float2bfloat16(v.w)).x;
    ((ushort4*)xb)[i] = o;
}

// One block = 8x4 query tile, 4 waves (256 thr); wave = one tile column,
// 8 queries serially. Fold accumulates into an LDS canvas; one atomic
// flush per block. wpsum gather: 8 batches of 4 rows, all 12 chunk-loads
// of a batch issued (named registers, separate unrolled loop) BEFORE any
// FMA -> MLP ~12+ per wave instead of ~1 (the round-2/5 structures were
// latency-bound here: ~96 serial gathers x ~800cyc = the whole runtime).
// NOTE: never cap VGPR tighter than ~(256,3): (256,4+) pins VGPR=64 and
// spills GBs of scratch (rounds 3/4/7). Spill signature: WRITE_SIZE >>
// 100 MB + VGPR stuck at 32/64.
__global__ __launch_bounds__(256, 3) void n3_tile_kernel(
    const unsigned short* __restrict__ xb,  // [N][147] bf16 packed
    const float* __restrict__ xe,           // [N, E]
    const float* __restrict__ ye,           // [Q, E]
    const float* __restrict__ log_temp,     // [H, W]
    const int*   __restrict__ cand,         // [Q, O]
    const int*   __restrict__ qindex,       // [Q]
    float*       __restrict__ vid)          // [KC, H, W] (pre-zeroed)
{
    __shared__ float canvas[CELEM];     // [KC][CHY][CHX]
    __shared__ float w_lds[NW][ON][8];  // per-wave weights, padded row
    __shared__ int   off_lds[NW][ON];   // per-wave candidate row offsets (elems)

    const int wib  = threadIdx.x >> 6;  // 0..3 = tile column
    const int lane = threadIdx.x & 63;
    const int by   = blockIdx.x / NBX;
    const int bx   = blockIdx.x - by * NBX;
    const int y0   = by * TQY;
    const int x0   = bx * TQX;

    for (int i = threadIdx.x; i < CELEM; i += 256) canvas[i] = 0.f;
    __syncthreads();

    for (int ty = 0; ty < TQY; ++ty) {
        const int q = (y0 + ty) * IW + (x0 + wib);

        const int qpix = qindex[q];
        const int qi = qpix / IW;
        const int qj = qpix - qi * IW;

        // ---- lt: mean over zero-padded 7x7 log_temp patch ----
        float ltv = 0.f;
        if (lane < PS * PS) {
            int pi = lane / PS, pj = lane % PS;
            int yy = qi + pi - PADR, xx = qj + pj - PADR;
            if (yy >= 0 && yy < IH && xx >= 0 && xx < IW)
                ltv = log_temp[yy * IW + xx];
        }
        #pragma unroll
        for (int s = 32; s >= 1; s >>= 1) ltv += __shfl_xor(ltv, s);
        const float itemp = expf(-ltv * (1.f / 49.f));   // 1/exp(lt)

        // ---- search: lane = o + 32*h; each half-wave does half of E ----
        const int o = lane & 31;
        const int h = lane >> 5;
        const int cidx = cand[q * ON + o];
        if (lane < ON) off_lds[wib][o] = cidx * FN;
        {
            const float4* xr = (const float4*)(xe + (size_t)cidx * EN) + h * 8;
            const float4* yr = (const float4*)(ye + (size_t)q * EN) + h * 8;
            float dot = 0.f, xn = 0.f, yn = 0.f;
            #pragma unroll
            for (int e = 0; e < 8; ++e) {
                float4 a = xr[e];
                float4 b = yr[e];
                dot += a.x * b.x + a.y * b.y + a.z * b.z + a.w * b.w;
                xn  += a.x * a.x + a.y * a.y + a.z * a.z + a.w * a.w;
                yn  += b.x * b.x + b.y * b.y + b.z * b.z + b.w * b.w;
            }
            float part = xn + yn - 2.f * dot;
            part += __shfl_xor(part, 32);    // both halves hold full d2
            // ---- NNN weights: 7 iterated softmaxes over 32-lane groups ----
            float logit = -part * itemp;
            float wk[KNB];
            #pragma unroll
            for (int k = 0; k < KNB; ++k) {
                float m = logit;
                #pragma unroll
                for (int s = 16; s >= 1; s >>= 1) m = fmaxf(m, __shfl_xor(m, s));
                float ev = expf(logit - m);
                float ssum = ev;
                #pragma unroll
                for (int s = 16; s >= 1; s >>= 1) ssum += __shfl_xor(ssum, s);
                float w = ev / ssum;
                wk[k] = w;
                logit += logf(fmaxf(1.f - w, 1e-6f));
            }
            if (lane < ON) {
                #pragma unroll
                for (int k = 0; k < KNB; ++k) w_lds[wib][lane][k] = wk[k];
            }
        }
        // wave-private LDS buffers: no __syncthreads needed

        // ---- wpsum: 8 batches of 4 rows; 12 loads batched before use ----
        float acc[3][KNB];
        #pragma unroll
        for (int it = 0; it < 3; ++it)
            #pragma unroll
            for (int k = 0; k < KNB; ++k) acc[it][k] = 0.f;

        #pragma unroll
        for (int b = 0; b < 8; ++b) {
            float xv0[4], xv1[4], xv2[4];
            #pragma unroll
            for (int r = 0; r < 4; ++r) {
                const unsigned short* rowp = xb + off_lds[wib][b * 4 + r];
                xv0[r] = bf16_to_f(rowp[lane]);
                xv1[r] = bf16_to_f(rowp[64 + lane]);
                xv2[r] = (lane < FN - 128) ? bf16_to_f(rowp[128 + lane]) : 0.f;
            }
            #pragma unroll
            for (int r = 0; r < 4; ++r) {
                const int oo = b * 4 + r;
                const float4 wa = *(const float4*)&w_lds[wib][oo][0];
                const float4 wb = *(const float4*)&w_lds[wib][oo][4];
                acc[0][0] += xv0[r] * wa.x;  acc[1][0] += xv1[r] * wa.x;  acc[2][0] += xv2[r] * wa.x;
                acc[0][1] += xv0[r] * wa.y;  acc[1][1] += xv1[r] * wa.y;  acc[2][1] += xv2[r] * wa.y;
                acc[0][2] += xv0[r] * wa.z;  acc[1][2] += xv1[r] * wa.z;  acc[2][2] += xv2[r] * wa.z;
                acc[0][3] += xv0[r] * wa.w;  acc[1][3] += xv1[r] * wa.w;  acc[2][3] += xv2[r] * wa.w;
                acc[0][4] += xv0[r] * wb.x;  acc[1][4] += xv1[r] * wb.x;  acc[2][4] += xv2[r] * wb.x;
                acc[0][5] += xv0[r] * wb.y;  acc[1][5] += xv1[r] * wb.y;  acc[2][5] += xv2[r] * wb.y;
                acc[0][6] += xv0[r] * wb.z;  acc[1][6] += xv1[r] * wb.z;  acc[2][6] += xv2[r] * wb.z;
            }
        }

        // ---- fold into LDS canvas ----
        #pragma unroll
        for (int it = 0; it < 3; ++it) {
            const int f = it * 64 + lane;
            if (f < FN) {
                const int c  = f / (PS * PS);
                const int r  = f - c * (PS * PS);
                const int pi = r / PS;
                const int pj = r - pi * PS;
                const int ly = qi + pi - y0;
                const int lx = qj + pj - x0;
                #pragma unroll
                for (int k = 0; k < KNB; ++k)
                    atomicAdd(&canvas[(k * CCH + c) * (CHY * CHX) + ly * CHX + lx],
                              acc[it][k]);
            }
        }
    }

    __syncthreads();

    // ---- flush canvas to global with crop bounds-check ----
    for (int i = threadIdx.x; i < CELEM; i += 256) {
        const float v = canvas[i];
        if (v != 0.f) {
            const int ch  = i / (CHY * CHX);
            const int rem = i - ch * (CHY * CHX);
            const int ly  = rem / CHX;
            const int lx  = rem - ly * CHX;
            const int gy  = y0 - PADR + ly;
            const int gx  = x0 - PADR + lx;
            if (gy >= 0 && gy < IH && gx >= 0 && gx < IW)
                atomicAdd(&vid[(size_t)ch * QN + gy * IW + gx], v);
        }
    }
}

// Fallback (ws too small): round-2-verified structure, fp32 x gather.
__global__ __launch_bounds__(256, 4) void n3_fallback_kernel(
    const float* __restrict__ x,
    const float* __restrict__ xe,
    const float* __restrict__ ye,
    const float* __restrict__ log_temp,
    const int*   __restrict__ cand,
    const int*   __restrict__ qindex,
    float*       __restrict__ vid)
{
    __shared__ float canvas[CELEM];
    __shared__ float w_lds[NW][ON][8];
    __shared__ int   off_lds[NW][ON];

    const int wib  = threadIdx.x >> 6;
    const int lane = threadIdx.x & 63;
    const int by   = blockIdx.x / NBX;
    const int bx   = blockIdx.x - by * NBX;
    const int y0   = by * TQY;
    const int x0   = bx * TQX;

    for (int i = threadIdx.x; i < CELEM; i += 256) canvas[i] = 0.f;
    __syncthreads();

    for (int ty = 0; ty < TQY; ++ty) {
        const int q = (y0 + ty) * IW + (x0 + wib);
        const int qpix = qindex[q];
        const int qi = qpix / IW;
        const int qj = qpix - qi * IW;

        float ltv = 0.f;
        if (lane < PS * PS) {
            int pi = lane / PS, pj = lane % PS;
            int yy = qi + pi - PADR, xx = qj + pj - PADR;
            if (yy >= 0 && yy < IH && xx >= 0 && xx < IW)
                ltv = log_temp[yy * IW + xx];
        }
        #pragma unroll
        for (int s = 32; s >= 1; s >>= 1) ltv += __shfl_xor(ltv, s);
        const float itemp = expf(-ltv * (1.f / 49.f));

        const int o = lane & 31;
        const int h = lane >> 5;
        const int cidx = cand[q * ON + o];
        if (lane < ON) off_lds[wib][o] = cidx * FN;
        {
            const float4* xr = (const float4*)(xe + (size_t)cidx * EN) + h * 8;
            const float4* yr = (const float4*)(ye + (size_t)q * EN) + h * 8;
            float dot = 0.f, xn = 0.f, yn = 0.f;
            #pragma unroll
            for (int e = 0; e < 8; ++e) {
                float4 a = xr[e];
                float4 b = yr[e];
                dot += a.x * b.x + a.y * b.y + a.z * b.z + a.w * b.w;
                xn  += a.x * a.x + a.y * a.y + a.z * a.z + a.w * a.w;
                yn  += b.x * b.x + b.y * b.y + b.z * b.z + b.w * b.w;
            }
            float part = xn + yn - 2.f * dot;
            part += __shfl_xor(part, 32);
            float logit = -part * itemp;
            float wk[KNB];
            #pragma unroll
            for (int k = 0; k < KNB; ++k) {
                float m = logit;
                #pragma unroll
                for (int s = 16; s >= 1; s >>= 1) m = fmaxf(m, __shfl_xor(m, s));
                float ev = expf(logit - m);
                float ssum = ev;
                #pragma unroll
                for (int s = 16; s >= 1; s >>= 1) ssum += __shfl_xor(ssum, s);
                float w = ev / ssum;
                wk[k] = w;
                logit += logf(fmaxf(1.f - w, 1e-6f));
            }
            if (lane < ON) {
                #pragma unroll
                for (int k = 0; k < KNB; ++k) w_lds[wib][lane][k] = wk[k];
            }
        }

        #pragma unroll
        for (int it = 0; it < 3; ++it) {
            const int f = it * 64 + lane;
            const bool act = f < FN;
            float acc[KNB];
            #pragma unroll
            for (int k = 0; k < KNB; ++k) acc[k] = 0.f;
            #pragma unroll 8
            for (int oo = 0; oo < ON; ++oo) {
                const int off = off_lds[wib][oo];
                const float xv = act ? x[off + f] : 0.f;
                #pragma unroll
                for (int k = 0; k < KNB; ++k) acc[k] += xv * w_lds[wib][oo][k];
            }
            if (act) {
                const int c  = f / (PS * PS);
                const int r  = f - c * (PS * PS);
                const int pi = r / PS;
                const int pj = r - pi * PS;
                const int ly = qi + pi - y0;
                const int lx = qj + pj - x0;
                #pragma unroll
                for (int k = 0; k < KNB; ++k)
                    atomicAdd(&canvas[(k * CCH + c) * (CHY * CHX) + ly * CHX + lx], acc[k]);
            }
        }
    }

    __syncthreads();

    for (int i = threadIdx.x; i < CELEM; i += 256) {
        const float v = canvas[i];
        if (v != 0.f) {
            const int ch  = i / (CHY * CHX);
            const int rem = i - ch * (CHY * CHX);
            const int ly  = rem / CHX;
            const int lx  = rem - ly * CHX;
            const int gy  = y0 - PADR + ly;
            const int gx  = x0 - PADR + lx;
            if (gy >= 0 && gy < IH && gx >= 0 && gx < IW)
                atomicAdd(&vid[(size_t)ch * QN + gy * IW + gx], v);
        }
    }
}

// wvid = fold(ones) with qindex = arange(H*W): separable border counts.
__global__ __launch_bounds__(256) void wvid_kernel(float* __restrict__ wvid) {
    int idx = blockIdx.x * blockDim.x + threadIdx.x;
    if (idx >= QN) return;
    int y  = idx / IW;
    int xx = idx - y * IW;
    int cy = min(PS - 1, y  + PADR) - max(0, y  - (IH - 1 - PADR)) + 1;
    int cx = min(PS - 1, xx + PADR) - max(0, xx - (IW - 1 - PADR)) + 1;
    float v = (float)(cy * cx);
    #pragma unroll
    for (int ch = 0; ch < KC; ++ch) wvid[(size_t)ch * QN + idx] = v;
}

extern "C" void kernel_launch(void* const* d_in, const int* in_sizes, int n_in,
                              void* d_out, int out_size, void* d_ws, size_t ws_size,
                              hipStream_t stream) {
    const float* x    = (const float*)d_in[0];
    const float* xe   = (const float*)d_in[1];
    const float* ye   = (const float*)d_in[2];
    const float* ltm  = (const float*)d_in[3];
    const int*   cand = (const int*)d_in[4];
    const int*   qidx = (const int*)d_in[5];

    float* vid  = (float*)d_out;
    float* wvid = vid + (size_t)KC * QN;

    // vid is accumulated with atomics -> must be zeroed every launch
    hipMemsetAsync(vid, 0, (size_t)KC * QN * sizeof(float), stream);

    const size_t xelems = (size_t)QN * FN;            // 9,633,792
    const size_t xbytes = xelems * sizeof(unsigned short);

    if (ws_size >= xbytes) {
        unsigned short* xb = (unsigned short*)d_ws;
        const int n4 = (int)(xelems / 4);
        conv_kernel<<<(n4 + 255) / 256, 256, 0, stream>>>(x, xb, n4);
        n3_tile_kernel<<<NBX * NBY, 256, 0, stream>>>(
            xb, xe, ye, ltm, cand, qidx, vid);
    } else {
        n3_fallback_kernel<<<NBX * NBY, 256, 0, stream>>>(
            x, xe, ye, ltm, cand, qidx, vid);
    }
    wvid_kernel<<<(QN + 255) / 256, 256, 0, stream>>>(wvid);
}

// Round 10
// 616.056 us; speedup vs baseline: 3.8253x; 3.8253x over previous
//
#include <hip/hip_runtime.h>
#include <hip/hip_bf16.h>
#include <math.h>

namespace {
constexpr int KNB  = 7;                  // neighbor volumes
constexpr int PS   = 7;                  // patch size
constexpr int CCH  = 3;                  // image channels
constexpr int IH   = 256;
constexpr int IW   = 256;
constexpr int PADR = 3;                  // PS/2
constexpr int QN   = IH * IW;            // 65536
constexpr int ON   = 32;                 // candidates per query
constexpr int EN   = 64;                 // embedding dim
constexpr int FN   = CCH * PS * PS;      // 147
constexpr int KC   = KNB * CCH;          // 21 output channels per map
constexpr int TQY  = 8;                  // tile rows
constexpr int TQX  = 4;                  // tile cols (= waves per block)
constexpr int CHY  = TQY + PS - 1;       // 14
constexpr int CHX  = TQX + PS - 1;       // 10
constexpr int CELEM = KC * CHY * CHX;    // 2940 canvas floats
constexpr int NW   = 4;                  // waves per block
constexpr int NBX  = IW / TQX;           // 64
constexpr int NBY  = IH / TQY;           // 32
constexpr int RPE  = 152;                // padded row elems: 304 B = 19 x 16B chunks
constexpr int RB   = RPE * 2;            // 304 bytes per row (16B aligned)
constexpr int NCH  = 19;                 // 16B chunks per row
constexpr int SROWS = 16;                // rows per stage half
constexpr int LROW = 164;                // LDS row stride in elems (328 B: bank spread)
}

__device__ __forceinline__ float bf16_to_f(unsigned short u) {
    union { unsigned int i; float f; } c;
    c.i = ((unsigned int)u) << 16;
    return c.f;
}

// x fp32 [N][147] -> bf16 [N][152] (304B rows, zero tail). Thread per 16B chunk.
__global__ __launch_bounds__(256) void conv_kernel(
    const float* __restrict__ x, unsigned short* __restrict__ xb)
{
    int t = blockIdx.x * blockDim.x + threadIdx.x;
    const int total = QN * NCH;
    if (t >= total) return;
    int row = t / NCH;
    int c   = t - row * NCH;
    const float* src = x + (size_t)row * FN;
    union { unsigned short u[8]; uint4 q; } v;
    #pragma unroll
    for (int j = 0; j < 8; ++j) {
        int e = c * 8 + j;
        float f = (e < FN) ? src[e] : 0.f;
        v.u[j] = __hip_bfloat16_raw(__float2bfloat16(f)).x;
    }
    *(uint4*)((char*)xb + (size_t)row * RB + c * 16) = v.q;
}

// One block = 8x4 query tile, 4 waves; wave = one tile column, 8 queries
// serially. wpsum gather is PER-LANE-ADDRESSED (lane -> (row,chunk)): one
// dwordx4 instruction carries 64 distinct addresses -> MLP ~100s without
// register pressure (wave-uniform row gathers were the latency wall:
// 96 x ~900cyc/query = entire runtime, rounds 2/5). Rows bounce through a
// 16-row wave-private LDS buffer (DS ops are in-order within a wave, so a
// single buffer is race-free); stage-B loads issue before FMA-A so their
// latency hides under compute.
// NOTE: never cap VGPR tighter than (256,3) (rounds 3/4 pinned 64 and
// spilled GBs); never fully unroll independent-gather batches (round 9:
// scheduler hoists all loads -> spill). Spill signature: WRITE >> 100MB.
__global__ __launch_bounds__(256, 3) void n3_tile_kernel(
    const unsigned short* __restrict__ xb,  // [N][152] bf16, 304B rows
    const float* __restrict__ xe,           // [N, E]
    const float* __restrict__ ye,           // [Q, E]
    const float* __restrict__ log_temp,     // [H, W]
    const int*   __restrict__ cand,         // [Q, O]
    const int*   __restrict__ qindex,       // [Q]
    float*       __restrict__ vid)          // [KC, H, W] (pre-zeroed)
{
    __shared__ float canvas[CELEM];                             // 11760 B
    __shared__ float w_lds[NW][ON][8];                          // 4096 B
    __shared__ __align__(16) unsigned short xstage[NW][SROWS * LROW]; // 20992 B

    const int wib  = threadIdx.x >> 6;  // 0..3 = tile column
    const int lane = threadIdx.x & 63;
    const int by   = blockIdx.x / NBX;
    const int bx   = blockIdx.x - by * NBX;
    const int y0   = by * TQY;
    const int x0   = bx * TQX;

    for (int i = threadIdx.x; i < CELEM; i += 256) canvas[i] = 0.f;
    __syncthreads();

    // stage slot mapping: s = lane + 64*t -> row r = s/19, chunk c = s%19
    int srow[5], scol[5], sact[5];
    #pragma unroll
    for (int t = 0; t < 5; ++t) {
        int s = lane + 64 * t;
        int r = s / NCH;
        scol[t] = s - r * NCH;
        sact[t] = (s < SROWS * NCH);
        srow[t] = sact[t] ? r : (SROWS - 1);
    }
    char* const xsb = (char*)&xstage[wib][0];

    for (int ty = 0; ty < TQY; ++ty) {
        const int q = (y0 + ty) * IW + (x0 + wib);

        const int qpix = qindex[q];
        const int qi = qpix / IW;
        const int qj = qpix - qi * IW;

        const int o = lane & 31;
        const int cidx = cand[q * ON + o];
        const int myoff = cidx * RB;    // byte offset of this lane's row

        // ---- stage A issue (rows 0-15): per-lane addresses, in flight
        //      behind the lt/search/softmax compute below ----
        uint4 ga0, ga1, ga2, ga3, ga4;
        {
            int r0 = __shfl(myoff, srow[0]);
            int r1 = __shfl(myoff, srow[1]);
            int r2 = __shfl(myoff, srow[2]);
            int r3 = __shfl(myoff, srow[3]);
            int r4 = __shfl(myoff, srow[4]);
            ga0 = *(const uint4*)((const char*)xb + r0 + scol[0] * 16);
            ga1 = *(const uint4*)((const char*)xb + r1 + scol[1] * 16);
            ga2 = *(const uint4*)((const char*)xb + r2 + scol[2] * 16);
            ga3 = *(const uint4*)((const char*)xb + r3 + scol[3] * 16);
            if (sact[4]) ga4 = *(const uint4*)((const char*)xb + r4 + scol[4] * 16);
        }

        // ---- lt: mean over zero-padded 7x7 log_temp patch ----
        float ltv = 0.f;
        if (lane < PS * PS) {
            int pi = lane / PS, pj = lane % PS;
            int yy = qi + pi - PADR, xx = qj + pj - PADR;
            if (yy >= 0 && yy < IH && xx >= 0 && xx < IW)
                ltv = log_temp[yy * IW + xx];
        }
        #pragma unroll
        for (int s = 32; s >= 1; s >>= 1) ltv += __shfl_xor(ltv, s);
        const float itemp = expf(-ltv * (1.f / 49.f));   // 1/exp(lt)

        // ---- search: lane = o + 32*h; each half-wave does half of E ----
        {
            const int h = lane >> 5;
            const float4* xr = (const float4*)(xe + (size_t)cidx * EN) + h * 8;
            const float4* yr = (const float4*)(ye + (size_t)q * EN) + h * 8;
            float dot = 0.f, xn = 0.f, yn = 0.f;
            #pragma unroll
            for (int e = 0; e < 8; ++e) {
                float4 a = xr[e];
                float4 b = yr[e];
                dot += a.x * b.x + a.y * b.y + a.z * b.z + a.w * b.w;
                xn  += a.x * a.x + a.y * a.y + a.z * a.z + a.w * a.w;
                yn  += b.x * b.x + b.y * b.y + b.z * b.z + b.w * b.w;
            }
            float part = xn + yn - 2.f * dot;
            part += __shfl_xor(part, 32);    // both halves hold full d2
            // ---- NNN weights: 7 iterated softmaxes over 32-lane groups ----
            float logit = -part * itemp;
            float wk[KNB];
            #pragma unroll
            for (int k = 0; k < KNB; ++k) {
                float m = logit;
                #pragma unroll
                for (int s = 16; s >= 1; s >>= 1) m = fmaxf(m, __shfl_xor(m, s));
                float ev = expf(logit - m);
                float ssum = ev;
                #pragma unroll
                for (int s = 16; s >= 1; s >>= 1) ssum += __shfl_xor(ssum, s);
                float w = ev / ssum;
                wk[k] = w;
                logit += logf(fmaxf(1.f - w, 1e-6f));
            }
            if (lane < ON) {
                #pragma unroll
                for (int k = 0; k < KNB; ++k) w_lds[wib][lane][k] = wk[k];
            }
        }
        // wave-private LDS buffers: no __syncthreads needed

        // ---- stage A write to LDS (waits its own vmcnt) ----
        if (true) {
            *(uint4*)(xsb + srow[0] * (LROW * 2) + scol[0] * 16) = ga0;
            *(uint4*)(xsb + srow[1] * (LROW * 2) + scol[1] * 16) = ga1;
            *(uint4*)(xsb + srow[2] * (LROW * 2) + scol[2] * 16) = ga2;
            *(uint4*)(xsb + srow[3] * (LROW * 2) + scol[3] * 16) = ga3;
            if (sact[4])
                *(uint4*)(xsb + srow[4] * (LROW * 2) + scol[4] * 16) = ga4;
        }

        // ---- stage B issue (rows 16-31): in flight during FMA A ----
        uint4 gb0, gb1, gb2, gb3, gb4;
        {
            int r0 = __shfl(myoff, 16 + srow[0]);
            int r1 = __shfl(myoff, 16 + srow[1]);
            int r2 = __shfl(myoff, 16 + srow[2]);
            int r3 = __shfl(myoff, 16 + srow[3]);
            int r4 = __shfl(myoff, 16 + srow[4]);
            gb0 = *(const uint4*)((const char*)xb + r0 + scol[0] * 16);
            gb1 = *(const uint4*)((const char*)xb + r1 + scol[1] * 16);
            gb2 = *(const uint4*)((const char*)xb + r2 + scol[2] * 16);
            gb3 = *(const uint4*)((const char*)xb + r3 + scol[3] * 16);
            if (sact[4]) gb4 = *(const uint4*)((const char*)xb + r4 + scol[4] * 16);
        }

        float acc[3][KNB];
        #pragma unroll
        for (int it = 0; it < 3; ++it)
            #pragma unroll
            for (int k = 0; k < KNB; ++k) acc[it][k] = 0.f;

        // ---- FMA A: rows 0-15 from LDS (f-major, conflict-free) ----
        #pragma unroll 4
        for (int r = 0; r < SROWS; ++r) {
            const unsigned short* xs = &xstage[wib][r * LROW];
            const float xv0 = bf16_to_f(xs[lane]);
            const float xv1 = bf16_to_f(xs[64 + lane]);
            const float xv2 = (lane < FN - 128) ? bf16_to_f(xs[128 + lane]) : 0.f;
            const float4 wa = *(const float4*)&w_lds[wib][r][0];
            const float4 wb = *(const float4*)&w_lds[wib][r][4];
            acc[0][0] += xv0 * wa.x;  acc[1][0] += xv1 * wa.x;  acc[2][0] += xv2 * wa.x;
            acc[0][1] += xv0 * wa.y;  acc[1][1] += xv1 * wa.y;  acc[2][1] += xv2 * wa.y;
            acc[0][2] += xv0 * wa.z;  acc[1][2] += xv1 * wa.z;  acc[2][2] += xv2 * wa.z;
            acc[0][3] += xv0 * wa.w;  acc[1][3] += xv1 * wa.w;  acc[2][3] += xv2 * wa.w;
            acc[0][4] += xv0 * wb.x;  acc[1][4] += xv1 * wb.x;  acc[2][4] += xv2 * wb.x;
            acc[0][5] += xv0 * wb.y;  acc[1][5] += xv1 * wb.y;  acc[2][5] += xv2 * wb.y;
            acc[0][6] += xv0 * wb.z;  acc[1][6] += xv1 * wb.z;  acc[2][6] += xv2 * wb.z;
        }

        // ---- stage B write (DS in-order after FMA A's reads) ----
        {
            *(uint4*)(xsb + srow[0] * (LROW * 2) + scol[0] * 16) = gb0;
            *(uint4*)(xsb + srow[1] * (LROW * 2) + scol[1] * 16) = gb1;
            *(uint4*)(xsb + srow[2] * (LROW * 2) + scol[2] * 16) = gb2;
            *(uint4*)(xsb + srow[3] * (LROW * 2) + scol[3] * 16) = gb3;
            if (sact[4])
                *(uint4*)(xsb + srow[4] * (LROW * 2) + scol[4] * 16) = gb4;
        }

        // ---- FMA B: rows 16-31 ----
        #pragma unroll 4
        for (int r = 0; r < SROWS; ++r) {
            const unsigned short* xs = &xstage[wib][r * LROW];
            const float xv0 = bf16_to_f(xs[lane]);
            const float xv1 = bf16_to_f(xs[64 + lane]);
            const float xv2 = (lane < FN - 128) ? bf16_to_f(xs[128 + lane]) : 0.f;
            const float4 wa = *(const float4*)&w_lds[wib][16 + r][0];
            const float4 wb = *(const float4*)&w_lds[wib][16 + r][4];
            acc[0][0] += xv0 * wa.x;  acc[1][0] += xv1 * wa.x;  acc[2][0] += xv2 * wa.x;
            acc[0][1] += xv0 * wa.y;  acc[1][1] += xv1 * wa.y;  acc[2][1] += xv2 * wa.y;
            acc[0][2] += xv0 * wa.z;  acc[1][2] += xv1 * wa.z;  acc[2][2] += xv2 * wa.z;
            acc[0][3] += xv0 * wa.w;  acc[1][3] += xv1 * wa.w;  acc[2][3] += xv2 * wa.w;
            acc[0][4] += xv0 * wb.x;  acc[1][4] += xv1 * wb.x;  acc[2][4] += xv2 * wb.x;
            acc[0][5] += xv0 * wb.y;  acc[1][5] += xv1 * wb.y;  acc[2][5] += xv2 * wb.y;
            acc[0][6] += xv0 * wb.z;  acc[1][6] += xv1 * wb.z;  acc[2][6] += xv2 * wb.z;
        }

        // ---- fold into LDS canvas ----
        #pragma unroll
        for (int it = 0; it < 3; ++it) {
            const int f = it * 64 + lane;
            if (f < FN) {
                const int c  = f / (PS * PS);
                const int r  = f - c * (PS * PS);
                const int pi = r / PS;
                const int pj = r - pi * PS;
                const int ly = qi + pi - y0;
                const int lx = qj + pj - x0;
                #pragma unroll
                for (int k = 0; k < KNB; ++k)
                    atomicAdd(&canvas[(k * CCH + c) * (CHY * CHX) + ly * CHX + lx],
                              acc[it][k]);
            }
        }
    }

    __syncthreads();

    // ---- flush canvas to global with crop bounds-check ----
    for (int i = threadIdx.x; i < CELEM; i += 256) {
        const float v = canvas[i];
        if (v != 0.f) {
            const int ch  = i / (CHY * CHX);
            const int rem = i - ch * (CHY * CHX);
            const int ly  = rem / CHX;
            const int lx  = rem - ly * CHX;
            const int gy  = y0 - PADR + ly;
            const int gx  = x0 - PADR + lx;
            if (gy >= 0 && gy < IH && gx >= 0 && gx < IW)
                atomicAdd(&vid[(size_t)ch * QN + gy * IW + gx], v);
        }
    }
}

// Fallback (ws too small): round-2-verified structure, fp32 x gather.
__global__ __launch_bounds__(256, 4) void n3_fallback_kernel(
    const float* __restrict__ x,
    const float* __restrict__ xe,
    const float* __restrict__ ye,
    const float* __restrict__ log_temp,
    const int*   __restrict__ cand,
    const int*   __restrict__ qindex,
    float*       __restrict__ vid)
{
    __shared__ float canvas[CELEM];
    __shared__ float w_lds[NW][ON][8];
    __shared__ int   off_lds[NW][ON];

    const int wib  = threadIdx.x >> 6;
    const int lane = threadIdx.x & 63;
    const int by   = blockIdx.x / NBX;
    const int bx   = blockIdx.x - by * NBX;
    const int y0   = by * TQY;
    const int x0   = bx * TQX;

    for (int i = threadIdx.x; i < CELEM; i += 256) canvas[i] = 0.f;
    __syncthreads();

    for (int ty = 0; ty < TQY; ++ty) {
        const int q = (y0 + ty) * IW + (x0 + wib);
        const int qpix = qindex[q];
        const int qi = qpix / IW;
        const int qj = qpix - qi * IW;

        float ltv = 0.f;
        if (lane < PS * PS) {
            int pi = lane / PS, pj = lane % PS;
            int yy = qi + pi - PADR, xx = qj + pj - PADR;
            if (yy >= 0 && yy < IH && xx >= 0 && xx < IW)
                ltv = log_temp[yy * IW + xx];
        }
        #pragma unroll
        for (int s = 32; s >= 1; s >>= 1) ltv += __shfl_xor(ltv, s);
        const float itemp = expf(-ltv * (1.f / 49.f));

        const int o = lane & 31;
        const int h = lane >> 5;
        const int cidx = cand[q * ON + o];
        if (lane < ON) off_lds[wib][o] = cidx * FN;
        {
            const float4* xr = (const float4*)(xe + (size_t)cidx * EN) + h * 8;
            const float4* yr = (const float4*)(ye + (size_t)q * EN) + h * 8;
            float dot = 0.f, xn = 0.f, yn = 0.f;
            #pragma unroll
            for (int e = 0; e < 8; ++e) {
                float4 a = xr[e];
                float4 b = yr[e];
                dot += a.x * b.x + a.y * b.y + a.z * b.z + a.w * b.w;
                xn  += a.x * a.x + a.y * a.y + a.z * a.z + a.w * a.w;
                yn  += b.x * b.x + b.y * b.y + b.z * b.z + b.w * b.w;
            }
            float part = xn + yn - 2.f * dot;
            part += __shfl_xor(part, 32);
            float logit = -part * itemp;
            float wk[KNB];
            #pragma unroll
            for (int k = 0; k < KNB; ++k) {
                float m = logit;
                #pragma unroll
                for (int s = 16; s >= 1; s >>= 1) m = fmaxf(m, __shfl_xor(m, s));
                float ev = expf(logit - m);
                float ssum = ev;
                #pragma unroll
                for (int s = 16; s >= 1; s >>= 1) ssum += __shfl_xor(ssum, s);
                float w = ev / ssum;
                wk[k] = w;
                logit += logf(fmaxf(1.f - w, 1e-6f));
            }
            if (lane < ON) {
                #pragma unroll
                for (int k = 0; k < KNB; ++k) w_lds[wib][lane][k] = wk[k];
            }
        }

        #pragma unroll
        for (int it = 0; it < 3; ++it) {
            const int f = it * 64 + lane;
            const bool act = f < FN;
            float acc[KNB];
            #pragma unroll
            for (int k = 0; k < KNB; ++k) acc[k] = 0.f;
            #pragma unroll 8
            for (int oo = 0; oo < ON; ++oo) {
                const int off = off_lds[wib][oo];
                const float xv = act ? x[off + f] : 0.f;
                #pragma unroll
                for (int k = 0; k < KNB; ++k) acc[k] += xv * w_lds[wib][oo][k];
            }
            if (act) {
                const int c  = f / (PS * PS);
                const int r  = f - c * (PS * PS);
                const int pi = r / PS;
                const int pj = r - pi * PS;
                const int ly = qi + pi - y0;
                const int lx = qj + pj - x0;
                #pragma unroll
                for (int k = 0; k < KNB; ++k)
                    atomicAdd(&canvas[(k * CCH + c) * (CHY * CHX) + ly * CHX + lx], acc[k]);
            }
        }
    }

    __syncthreads();

    for (int i = threadIdx.x; i < CELEM; i += 256) {
        const float v = canvas[i];
        if (v != 0.f) {
            const int ch  = i / (CHY * CHX);
            const int rem = i - ch * (CHY * CHX);
            const int ly  = rem / CHX;
            const int lx  = rem - ly * CHX;
            const int gy  = y0 - PADR + ly;
            const int gx  = x0 - PADR + lx;
            if (gy >= 0 && gy < IH && gx >= 0 && gx < IW)
                atomicAdd(&vid[(size_t)ch * QN + gy * IW + gx], v);
        }
    }
}

// wvid = fold(ones) with qindex = arange(H*W): separable border counts.
__global__ __launch_bounds__(256) void wvid_kernel(float* __restrict__ wvid) {
    int idx = blockIdx.x * blockDim.x + threadIdx.x;
    if (idx >= QN) return;
    int y  = idx / IW;
    int xx = idx - y * IW;
    int cy = min(PS - 1, y  + PADR) - max(0, y  - (IH - 1 - PADR)) + 1;
    int cx = min(PS - 1, xx + PADR) - max(0, xx - (IW - 1 - PADR)) + 1;
    float v = (float)(cy * cx);
    #pragma unroll
    for (int ch = 0; ch < KC; ++ch) wvid[(size_t)ch * QN + idx] = v;
}

extern "C" void kernel_launch(void* const* d_in, const int* in_sizes, int n_in,
                              void* d_out, int out_size, void* d_ws, size_t ws_size,
                              hipStream_t stream) {
    const float* x    = (const float*)d_in[0];
    const float* xe   = (const float*)d_in[1];
    const float* ye   = (const float*)d_in[2];
    const float* ltm  = (const float*)d_in[3];
    const int*   cand = (const int*)d_in[4];
    const int*   qidx = (const int*)d_in[5];

    float* vid  = (float*)d_out;
    float* wvid = vid + (size_t)KC * QN;

    // vid is accumulated with atomics -> must be zeroed every launch
    hipMemsetAsync(vid, 0, (size_t)KC * QN * sizeof(float), stream);

    const size_t xbytes = (size_t)QN * RB;   // 19.9 MB

    if (ws_size >= xbytes) {
        unsigned short* xb = (unsigned short*)d_ws;
        const int nconv = QN * NCH;
        conv_kernel<<<(nconv + 255) / 256, 256, 0, stream>>>(x, xb);
        n3_tile_kernel<<<NBX * NBY, 256, 0, stream>>>(
            xb, xe, ye, ltm, cand, qidx, vid);
    } else {
        n3_fallback_kernel<<<NBX * NBY, 256, 0, stream>>>(
            x, xe, ye, ltm, cand, qidx, vid);
    }
    wvid_kernel<<<(QN + 255) / 256, 256, 0, stream>>>(wvid);
}